// Round 2
// baseline (199.872 us; speedup 1.0000x reference)
//
#include <hip/hip_runtime.h>
#include <hip/hip_bf16.h>
#include <stdint.h>

#define C_DIM 256
#define N_DIM 4096
#define B_DIM 4

typedef __attribute__((ext_vector_type(8))) short s16x8;   // 8 bf16
typedef __attribute__((ext_vector_type(4))) short s16x4;   // 4 bf16
typedef __attribute__((ext_vector_type(4))) float f32x4;
typedef __attribute__((ext_vector_type(16))) float f32x16;

static __device__ __forceinline__ short f2bs(float f) {
    __bf16 h = (__bf16)f;                 // RNE f32->bf16
    return __builtin_bit_cast(short, h);
}

// ---------------------------------------------------------------------------
// Kernel 0: transpose+convert x,y -> xT,yT [B][N][C] bf16; convert weights.
// ---------------------------------------------------------------------------
__global__ __launch_bounds__(256)
void prep_kernel(const float* __restrict__ x, const float* __restrict__ y,
                 const float* __restrict__ wq, const float* __restrict__ wk,
                 const float* __restrict__ wv,
                 short* __restrict__ xT, short* __restrict__ yT,
                 short* __restrict__ wb)
{
    int bid = blockIdx.x;
    int t = threadIdx.x;
    if (bid < 2048) {
        const float* src = (bid < 1024) ? x : y;
        short* dst = (bid < 1024) ? xT : yT;
        int id = bid & 1023;
        int ct = id & 3;            // 4 c-tiles of 64
        int nt = (id >> 2) & 63;    // 64 n-tiles of 64
        int b  = id >> 8;           // 4 batches
        int n0 = nt * 64, c0 = ct * 64;
        __shared__ short T[64][66]; // odd dword stride -> conflict-free
        int l = t & 63;
        int wv_ = t >> 6;
        #pragma unroll
        for (int p = 0; p < 16; ++p) {
            int c = wv_ + p * 4;
            float v = src[((size_t)(b * C_DIM + c0 + c)) * N_DIM + n0 + l];
            T[l][c] = f2bs(v);
        }
        __syncthreads();
        #pragma unroll
        for (int p = 0; p < 16; ++p) {
            int n = wv_ + p * 4;
            dst[((size_t)(b * N_DIM + n0 + n)) * C_DIM + c0 + l] = T[n][l];
        }
    } else {
        // weights: 96 blocks x 2048 elems
        int id = bid - 2048;
        const float* w = (id < 32) ? wq : (id < 64) ? wk : wv;
        short* dst = wb + (size_t)(id / 32) * (C_DIM * C_DIM);
        int off = (id & 31) * 2048 + t * 8;
        f32x4 a  = *(const f32x4*)(w + off);
        f32x4 b4 = *(const f32x4*)(w + off + 4);
        s16x8 r;
        r[0]=f2bs(a[0]);  r[1]=f2bs(a[1]);  r[2]=f2bs(a[2]);  r[3]=f2bs(a[3]);
        r[4]=f2bs(b4[0]); r[5]=f2bs(b4[1]); r[6]=f2bs(b4[2]); r[7]=f2bs(b4[3]);
        *(s16x8*)(dst + off) = r;
    }
}

// ---------------------------------------------------------------------------
// Kernel 1: projections. Qb,Kb = [B][N][256]; Vb = [B][256][N].
// Q is pre-scaled by log2(e) so attention softmax can use exp2 directly.
// ---------------------------------------------------------------------------
__global__ __launch_bounds__(256)
void proj_kernel(const short* __restrict__ xT, const short* __restrict__ yT,
                 const short* __restrict__ wb,
                 short* __restrict__ Qb, short* __restrict__ Kb,
                 short* __restrict__ Vb)
{
    int bid = blockIdx.x;              // 3072 = 12 * 64 * 4
    int ot = bid & 3;
    int nt = (bid >> 2) & 63;
    int bp = bid >> 8;                 // 0..11 = b*3 + p
    int b = bp / 3, p = bp % 3;
    int n0 = nt * 64, o0 = ot * 64;
    const short* src = (p == 0) ? xT : yT;
    const short* w = wb + (size_t)p * C_DIM * C_DIM;

    __shared__ __align__(16) short Xs[64][264];

    int t = threadIdx.x;
    const short* srcb = src + (size_t)(b * N_DIM + n0) * C_DIM;
    #pragma unroll
    for (int pas = 0; pas < 8; ++pas) {
        int slot = pas * 256 + t;
        int row = slot >> 5, ck = slot & 31;
        *(s16x8*)&Xs[row][ck * 8] = *(const s16x8*)&srcb[(size_t)row * C_DIM + ck * 8];
    }
    __syncthreads();

    int lane = t & 63;
    int wid = t >> 6;
    int m = lane & 15, q = lane >> 4;
    f32x4 acc[4] = {};

    if (p < 2) {
        #pragma unroll
        for (int kk = 0; kk < 8; ++kk) {
            s16x8 af = *(const s16x8*)&Xs[wid * 16 + m][kk * 32 + q * 8];
            #pragma unroll
            for (int ob = 0; ob < 4; ++ob) {
                s16x8 bf = *(const s16x8*)&w[(size_t)(o0 + ob * 16 + m) * C_DIM + kk * 32 + q * 8];
                acc[ob] = __builtin_amdgcn_mfma_f32_16x16x32_bf16(af, bf, acc[ob], 0, 0, 0);
            }
        }
        float sc = (p == 0) ? 1.4426950408889634f : 1.0f;  // log2(e) for Q
        short* dst = ((p == 0) ? Qb : Kb) + (size_t)b * N_DIM * C_DIM;
        #pragma unroll
        for (int ob = 0; ob < 4; ++ob)
            #pragma unroll
            for (int r = 0; r < 4; ++r) {
                int n = n0 + wid * 16 + q * 4 + r;
                int o = o0 + ob * 16 + m;
                dst[(size_t)n * C_DIM + o] = f2bs(acc[ob][r] * sc);
            }
    } else {
        #pragma unroll
        for (int kk = 0; kk < 8; ++kk) {
            s16x8 af = *(const s16x8*)&w[(size_t)(o0 + wid * 16 + m) * C_DIM + kk * 32 + q * 8];
            #pragma unroll
            for (int nb = 0; nb < 4; ++nb) {
                s16x8 bf = *(const s16x8*)&Xs[nb * 16 + m][kk * 32 + q * 8];
                acc[nb] = __builtin_amdgcn_mfma_f32_16x16x32_bf16(af, bf, acc[nb], 0, 0, 0);
            }
        }
        short* dst = Vb + (size_t)b * C_DIM * N_DIM;
        #pragma unroll
        for (int nb = 0; nb < 4; ++nb)
            #pragma unroll
            for (int r = 0; r < 4; ++r) {
                int o = o0 + wid * 16 + q * 4 + r;
                int n = n0 + nb * 16 + m;
                dst[(size_t)o * N_DIM + n] = f2bs(acc[nb][r]);
            }
    }
}

// ---------------------------------------------------------------------------
// Kernel 2: flash attention + epilogue. KVBLK=256, 8 symmetric waves.
//
// K and V are NOT staged in LDS: fragments are read global->reg and hit the
// XCD-local L2 (batch K+V = 4MB, 32 same-batch blocks/XCD via swizzle).
// LDS holds only Q (staged once, XOR-swizzled) and P (double-buffered,
// XOR-swizzled), plus tiny m/s partials. 2 barriers per 256-key tile; no
// barrier between PV(jt) and QK(jt+1) so waves desync and overlap.
//
// Wave w: QK j-block = w (A = K rows w*32+il, shared by both q-half MFMAs);
//         PV c-strip = w*32 (A = V rows, B = P from LDS).
// Lane (il,hi) tracks softmax state for q = il (A) and q = 32+il (B).
// ---------------------------------------------------------------------------
__global__ __launch_bounds__(512, 2)
void attn_kernel(const short* __restrict__ Qb, const short* __restrict__ Kb,
                 const short* __restrict__ Vb, const float* __restrict__ x,
                 const float* __restrict__ gamma, float* __restrict__ out)
{
    int bid0 = blockIdx.x;
    int bid = (bid0 & 7) * 32 + (bid0 >> 3);   // XCD swizzle: 32 same-batch blocks/XCD
    int b = bid >> 6, it = bid & 63;
    int i0 = it * 64;

    int t = threadIdx.x;
    int w = t >> 6;          // wave 0..7: QK j-block, PV c-strip
    int lane = t & 63;
    int il = lane & 31;
    int hi = lane >> 5;
    int xsw = il & 15;       // 16B-granule XOR swizzle key

    __shared__ __align__(16) short Qs[64][256];     // 32 KB, swizzled granules
    __shared__ __align__(16) short Ps[2][64][256];  // 64 KB, swizzled granules
    __shared__ float mpart[8][64];                  // [jb][q]
    __shared__ float spart[8][64];

    const short* Kp = Kb + (size_t)b * N_DIM * C_DIM;
    const short* Vp = Vb + (size_t)b * C_DIM * N_DIM;

    // stage Q once: row = t>>3 (0..63), 4 granules of 16B per thread
    {
        int row = t >> 3;
        const short* qsrc = Qb + (size_t)b * N_DIM * C_DIM + (size_t)(i0 + row) * C_DIM;
        #pragma unroll
        for (int p = 0; p < 4; ++p) {
            int g = (t & 7) * 4 + p;
            s16x8 v = *(const s16x8*)&qsrc[g * 8];
            *(s16x8*)&Qs[row][(g ^ (row & 15)) * 8] = v;
        }
    }

    // per-lane running global pointers (advance per jt; loads use imm offsets)
    const short* kPtr = Kp + (size_t)(w * 32 + il) * C_DIM + hi * 8;  // K row j
    const short* vPtr = Vp + (size_t)(w * 32 + il) * N_DIM + hi * 8;  // V row c

    f32x16 acc0 = {}, acc1 = {};
    float mrunA = -3e38f, mrunB = -3e38f, srunA = 0.f, srunB = 0.f;

    __syncthreads();   // Qs ready

    for (int jt = 0; jt < 16; ++jt) {
        // ---- Phase A: QK. K direct from global (L2), Q from LDS -----------
        s16x8 af[16];
        #pragma unroll
        for (int kk = 0; kk < 16; ++kk)
            af[kk] = *(const s16x8*)&kPtr[kk * 16];
        kPtr += 256 * C_DIM;
        f32x16 sv0 = {}, sv1 = {};
        __builtin_amdgcn_s_setprio(1);
        #pragma unroll
        for (int kk = 0; kk < 16; ++kk) {
            int qc = ((kk * 2 + hi) ^ xsw) * 8;
            s16x8 b0 = *(const s16x8*)&Qs[il][qc];
            s16x8 b1 = *(const s16x8*)&Qs[32 + il][qc];
            sv0 = __builtin_amdgcn_mfma_f32_32x32x16_bf16(af[kk], b0, sv0, 0, 0, 0);
            sv1 = __builtin_amdgcn_mfma_f32_32x32x16_bf16(af[kk], b1, sv1, 0, 0, 0);
        }
        __builtin_amdgcn_s_setprio(0);
        float tA = sv0[0], tB = sv1[0];
        #pragma unroll
        for (int r = 1; r < 16; ++r) { tA = fmaxf(tA, sv0[r]); tB = fmaxf(tB, sv1[r]); }
        tA = fmaxf(tA, __shfl_xor(tA, 32, 64));
        tB = fmaxf(tB, __shfl_xor(tB, 32, 64));
        if (hi == 0) { mpart[w][il] = tA; mpart[w][32 + il] = tB; }
        __syncthreads();   // bar1: mpart ready

        // ---- Phase B: V prefetch (latency hides under softmax), softmax ---
        s16x8 vf[16];
        #pragma unroll
        for (int kc = 0; kc < 16; ++kc)
            vf[kc] = *(const s16x8*)&vPtr[kc * 16];
        vPtr += 256;

        float mA = mrunA, mB = mrunB;
        #pragma unroll
        for (int j = 0; j < 8; ++j) {
            mA = fmaxf(mA, mpart[j][il]);
            mB = fmaxf(mB, mpart[j][32 + il]);
        }
        float alphaA = exp2f(mrunA - mA);
        float alphaB = exp2f(mrunB - mB);
        mrunA = mA; mrunB = mB;
        if (__any(alphaA != 1.f)) {         // T13: skip rescale if max unchanged
            #pragma unroll
            for (int r = 0; r < 16; ++r) acc0[r] *= alphaA;
        }
        if (__any(alphaB != 1.f)) {
            #pragma unroll
            for (int r = 0; r < 16; ++r) acc1[r] *= alphaB;
        }
        float tsA = 0.f, tsB = 0.f;
        #pragma unroll
        for (int r = 0; r < 16; ++r) {
            float pA = exp2f(sv0[r] - mA); sv0[r] = pA; tsA += pA;
            float pB = exp2f(sv1[r] - mB); sv1[r] = pB; tsB += pB;
        }
        tsA += __shfl_xor(tsA, 32, 64);
        tsB += __shfl_xor(tsB, 32, 64);
        if (hi == 0) { spart[w][il] = tsA; spart[w][32 + il] = tsB; }
        // P rows j = w*32 + 8g + 4hi + (0..3); store P^T as Ps[q][j] swizzled
        short (*Pw)[256] = Ps[jt & 1];
        #pragma unroll
        for (int g = 0; g < 4; ++g) {
            s16x4 p0, p1;
            p0[0]=f2bs(sv0[4*g+0]); p0[1]=f2bs(sv0[4*g+1]);
            p0[2]=f2bs(sv0[4*g+2]); p0[3]=f2bs(sv0[4*g+3]);
            p1[0]=f2bs(sv1[4*g+0]); p1[1]=f2bs(sv1[4*g+1]);
            p1[2]=f2bs(sv1[4*g+2]); p1[3]=f2bs(sv1[4*g+3]);
            int gr = ((w * 4 + g) ^ xsw) * 8 + hi * 4;
            *(s16x4*)&Pw[il][gr]      = p0;
            *(s16x4*)&Pw[32 + il][gr] = p1;
        }
        __syncthreads();   // bar2: Ps + spart ready

        // ---- Phase C: PV. V from regs, P from LDS -------------------------
        float sA = 0.f, sB = 0.f;
        #pragma unroll
        for (int j = 0; j < 8; ++j) { sA += spart[j][il]; sB += spart[j][32 + il]; }
        srunA = srunA * alphaA + sA;
        srunB = srunB * alphaB + sB;
        const short (*Pr)[256] = Ps[jt & 1];
        __builtin_amdgcn_s_setprio(1);
        #pragma unroll
        for (int kc = 0; kc < 16; ++kc) {
            int pc = ((kc * 2 + hi) ^ xsw) * 8;
            s16x8 b0 = *(const s16x8*)&Pr[il][pc];
            s16x8 b1 = *(const s16x8*)&Pr[32 + il][pc];
            acc0 = __builtin_amdgcn_mfma_f32_32x32x16_bf16(vf[kc], b0, acc0, 0, 0, 0);
            acc1 = __builtin_amdgcn_mfma_f32_32x32x16_bf16(vf[kc], b1, acc1, 0, 0, 0);
        }
        __builtin_amdgcn_s_setprio(0);
        // no barrier here: Ps double-buffered; waves desync into next QK
    }

    // epilogue: O^T layout -> out[b][c][i], residual + gamma scale
    float g = gamma[0];
    float invA = 1.f / srunA;
    float invB = 1.f / srunB;
    #pragma unroll
    for (int r = 0; r < 16; ++r) {
        int c = w * 32 + (r & 3) + 8 * (r >> 2) + 4 * hi;
        size_t idxA = ((size_t)(b * C_DIM + c)) * N_DIM + i0 + il;
        out[idxA] = g * acc0[r] * invA + x[idxA];
        size_t idxB = idxA + 32;
        out[idxB] = g * acc1[r] * invB + x[idxB];
    }
}

// ---------------------------------------------------------------------------
extern "C" void kernel_launch(void* const* d_in, const int* in_sizes, int n_in,
                              void* d_out, int out_size, void* d_ws, size_t ws_size,
                              hipStream_t stream) {
    const float* x  = (const float*)d_in[0];
    const float* y  = (const float*)d_in[1];
    const float* wq = (const float*)d_in[2];
    const float* wk = (const float*)d_in[3];
    const float* wv = (const float*)d_in[4];
    const float* gm = (const float*)d_in[5];
    float* out = (float*)d_out;

    char* ws = (char*)d_ws;
    const size_t SZ = (size_t)B_DIM * N_DIM * C_DIM * sizeof(short); // 8 MB
    short* xT = (short*)(ws);
    short* yT = (short*)(ws + SZ);
    short* Qb = (short*)(ws + 2 * SZ);
    short* Kb = (short*)(ws + 3 * SZ);
    short* Vb = (short*)(ws + 4 * SZ);
    short* wb = (short*)(ws + 5 * SZ); // 384 KB

    prep_kernel<<<dim3(2048 + 96), dim3(256), 0, stream>>>(x, y, wq, wk, wv, xT, yT, wb);
    proj_kernel<<<dim3(3072), dim3(256), 0, stream>>>(xT, yT, wb, Qb, Kb, Vb);
    attn_kernel<<<dim3(256), dim3(512), 0, stream>>>(Qb, Kb, Vb, x, gm, out);
}